// Round 1
// baseline (1574.886 us; speedup 1.0000x reference)
//
#include <hip/hip_runtime.h>

#define BB 2
#define NN 1024
#define CC 768
#define HH 12
#define DD 64
#define SCALE_F 0.125f

// ---------------------------------------------------------------------------
// Generic tiled GEMM: out[M,Nc] = A[M,K] @ W[Nc,K]^T (+ bias[Nc])
// 32x32 tile, BK=32, 256 threads, 2x2 outputs per thread.
// M,Nc,K all multiples of 32 here, so no bounds checks.
// ---------------------------------------------------------------------------
__global__ __launch_bounds__(256) void gemm_bt(
    const float* __restrict__ A, const float* __restrict__ W,
    const float* __restrict__ bias, float* __restrict__ out,
    int M, int Nc, int K) {
  __shared__ float As[32][33];
  __shared__ float Bs[32][33];
  const int tx = threadIdx.x & 15;
  const int ty = threadIdx.x >> 4;
  const int row0 = blockIdx.y * 32;
  const int col0 = blockIdx.x * 32;
  float acc00 = 0.f, acc01 = 0.f, acc10 = 0.f, acc11 = 0.f;
  for (int k0 = 0; k0 < K; k0 += 32) {
    const int t = threadIdx.x;
#pragma unroll
    for (int i = 0; i < 4; i++) {
      int idx = t + i * 256;       // 0..1023
      int r = idx >> 5, cc = idx & 31;
      As[r][cc] = A[(row0 + r) * K + k0 + cc];
      Bs[r][cc] = W[(col0 + r) * K + k0 + cc];
    }
    __syncthreads();
#pragma unroll
    for (int k = 0; k < 32; k++) {
      float a0 = As[ty * 2][k], a1 = As[ty * 2 + 1][k];
      float b0 = Bs[tx * 2][k], b1 = Bs[tx * 2 + 1][k];
      acc00 += a0 * b0; acc01 += a0 * b1;
      acc10 += a1 * b0; acc11 += a1 * b1;
    }
    __syncthreads();
  }
  int r0 = row0 + ty * 2, c0 = col0 + tx * 2;
  float bb0 = bias ? bias[c0] : 0.f;
  float bb1 = bias ? bias[c0 + 1] : 0.f;
  out[r0 * Nc + c0] = acc00 + bb0;
  out[r0 * Nc + c0 + 1] = acc01 + bb1;
  out[(r0 + 1) * Nc + c0] = acc10 + bb0;
  out[(r0 + 1) * Nc + c0 + 1] = acc11 + bb1;
}

// ---------------------------------------------------------------------------
// q/k rows: r = silu(z)+0.5, L2-normalized over D=64. One wave per row.
// rows enumerated over s in {0(q),1(k)} x b x n x h.
// qkv layout: [B, N, 3, H, D] flat = ((b*N+n)*3+s)*C + h*D + d
// ---------------------------------------------------------------------------
__global__ __launch_bounds__(256) void qknorm_kernel(float* __restrict__ qkv) {
  const int wid = (blockIdx.x * blockDim.x + threadIdx.x) >> 6;
  const int lane = threadIdx.x & 63;
  // wid in [0, 2*B*N*H)
  int s = wid & 1;
  int tmp = wid >> 1;
  int h = tmp % HH; tmp /= HH;
  int n = tmp % NN;
  int b = tmp / NN;
  float* p = qkv + (((size_t)(b * NN + n) * 3 + s) * CC) + h * DD + lane;
  float z = *p;
  float sig = 1.f / (1.f + __expf(-z));
  float r = z * sig + 0.5f;
  float ss = r * r;
#pragma unroll
  for (int off = 32; off >= 1; off >>= 1) ss += __shfl_xor(ss, off, 64);
  *p = r * rsqrtf(ss);
}

// ---------------------------------------------------------------------------
// Gate: loga[b,h,n] = (n==0) ? 0 : log(1 - sigmoid(x[b,n,:]·Wa[h,:] + ba[h]))
// one thread per (b,n,h)
// ---------------------------------------------------------------------------
__global__ __launch_bounds__(256) void gate_kernel(
    const float* __restrict__ x, const float* __restrict__ Wa,
    const float* __restrict__ ba, float* __restrict__ loga) {
  int idx = blockIdx.x * blockDim.x + threadIdx.x;
  if (idx >= BB * NN * HH) return;
  int h = idx % HH;
  int n = (idx / HH) % NN;
  int b = idx / (HH * NN);
  const float* xr = x + (size_t)(b * NN + n) * CC;
  const float* wr = Wa + h * CC;
  float acc = 0.f;
  for (int k = 0; k < CC; k++) acc += xr[k] * wr[k];
  acc += ba[h];
  float a = 1.f - 1.f / (1.f + __expf(-acc));
  float la = (n == 0) ? 0.f : __logf(a);
  loga[(b * HH + h) * NN + n] = la;
}

// ---------------------------------------------------------------------------
// Per-(b,h) inclusive scan of loga -> c[b,h,m], m=0..N (c[0]=0).
// One block of 1024 threads per (b,h). Hillis-Steele in LDS.
// ---------------------------------------------------------------------------
__global__ __launch_bounds__(1024) void scan_kernel(
    const float* __restrict__ loga, float* __restrict__ c) {
  __shared__ float s[NN];
  const int bh = blockIdx.x;
  const int t = threadIdx.x;
  s[t] = loga[bh * NN + t];
  __syncthreads();
#pragma unroll
  for (int off = 1; off < NN; off <<= 1) {
    float prev = (t >= off) ? s[t - off] : 0.f;
    __syncthreads();
    s[t] += prev;
    __syncthreads();
  }
  c[bh * (NN + 1) + t + 1] = s[t];
  if (t == 0) c[bh * (NN + 1)] = 0.f;
}

// ---------------------------------------------------------------------------
// Fused attention. One wave (64 threads) per (b,h,i) query row.
//   pass1: s_j = q_i·k_j, attn_j = s_j*SCALE*M[i,j]  (M from cumsum c)
//   pass2: out_d = sum_j attn_j * v[j,d] / (rowsum + 1e-6)
// ---------------------------------------------------------------------------
__global__ __launch_bounds__(64) void attn_kernel(
    const float* __restrict__ qkv, const float* __restrict__ c,
    float* __restrict__ attnout) {
  __shared__ float ktile[64][65];
  __shared__ float arow[NN];
  __shared__ float qs[64];
  const int blk = blockIdx.x;           // (b*H + h)*N + i
  const int i = blk % NN;
  const int h = (blk / NN) % HH;
  const int b = blk / (NN * HH);
  const int lane = threadIdx.x;

  qs[lane] = qkv[((size_t)(b * NN + i) * 3 + 0) * CC + h * DD + lane];
  const float* cbh = c + (b * HH + h) * (NN + 1);
  const float ci = cbh[i], ci1 = cbh[i + 1];
  float lsum = 0.f;

  for (int j0 = 0; j0 < NN; j0 += 64) {
    __syncthreads();
#pragma unroll 8
    for (int jj = 0; jj < 64; jj++) {
      ktile[jj][lane] =
          qkv[((size_t)(b * NN + (j0 + jj)) * 3 + 1) * CC + h * DD + lane];
    }
    __syncthreads();
    const int j = j0 + lane;
    float s = 0.f;
#pragma unroll 16
    for (int d = 0; d < 64; d++) s += qs[d] * ktile[lane][d];
    float cj = cbh[j], cj1 = cbh[j + 1];
    float m = (j < i) ? __expf(ci - cj) : (j > i) ? __expf(cj1 - ci1) : 1.0f;
    float av = s * SCALE_F * m;
    arow[j] = av;
    lsum += av;
  }
#pragma unroll
  for (int off = 32; off >= 1; off >>= 1) lsum += __shfl_xor(lsum, off, 64);
  const float inv = 1.f / (lsum + 1e-6f);
  __syncthreads();

  float acc = 0.f;
  const float* vbase = qkv + 2 * CC + h * DD + lane;
#pragma unroll 8
  for (int j = 0; j < NN; j++) {
    acc += arow[j] * vbase[(size_t)(b * NN + j) * 3 * CC];
  }
  attnout[(size_t)(b * NN + i) * CC + h * DD + lane] = acc * inv;
}

// ---------------------------------------------------------------------------
extern "C" void kernel_launch(void* const* d_in, const int* in_sizes, int n_in,
                              void* d_out, int out_size, void* d_ws,
                              size_t ws_size, hipStream_t stream) {
  const float* x = (const float*)d_in[0];      // [B,N,C]
  const float* Wqkv = (const float*)d_in[1];   // [3C,C]
  const float* Wa = (const float*)d_in[2];     // [H,C]
  const float* ba = (const float*)d_in[3];     // [H]
  const float* Wproj = (const float*)d_in[4];  // [C,C]
  const float* bproj = (const float*)d_in[5];  // [C]
  float* out = (float*)d_out;                  // [B,N,C]

  float* qkv = (float*)d_ws;                         // B*N*3C = 4,718,592
  float* attnout = qkv + (size_t)BB * NN * 3 * CC;   // B*N*C  = 1,572,864
  float* loga = attnout + (size_t)BB * NN * CC;      // B*H*N  = 24,576
  float* cbuf = loga + (size_t)BB * HH * NN;         // B*H*(N+1) = 24,600

  // 1) qkv = x @ Wqkv^T
  {
    dim3 grid(3 * CC / 32, BB * NN / 32);
    gemm_bt<<<grid, 256, 0, stream>>>(x, Wqkv, nullptr, qkv,
                                      BB * NN, 3 * CC, CC);
  }
  // 2) silu-shift-L2norm q and k in place
  {
    int rows = 2 * BB * NN * HH;                // 49152 waves
    qknorm_kernel<<<rows * 64 / 256, 256, 0, stream>>>(qkv);
  }
  // 3) gates
  gate_kernel<<<(BB * NN * HH + 255) / 256, 256, 0, stream>>>(x, Wa, ba, loga);
  // 4) cumsum -> c
  scan_kernel<<<BB * HH, 1024, 0, stream>>>(loga, cbuf);
  // 5) fused masked attention + sum-normalization
  attn_kernel<<<BB * HH * NN, 64, 0, stream>>>(qkv, cbuf, attnout);
  // 6) out = attnout @ Wproj^T + bproj
  {
    dim3 grid(CC / 32, BB * NN / 32);
    gemm_bt<<<grid, 256, 0, stream>>>(attnout, Wproj, bproj, out,
                                      BB * NN, CC, CC);
  }
}

// Round 3
// 454.071 us; speedup vs baseline: 3.4684x; 3.4684x over previous
//
#include <hip/hip_runtime.h>
#include <hip/hip_bf16.h>

#define BB 2
#define NN 1024
#define CC 768
#define HH 12
#define DD 64
#define SCALE_F 0.125f

typedef __attribute__((ext_vector_type(8))) __bf16 bf16x8;
typedef __attribute__((ext_vector_type(8))) unsigned short u16x8;
typedef __attribute__((ext_vector_type(4))) float f32x4;

static __device__ __forceinline__ bf16x8 as_bf16x8(u16x8 v) {
  return __builtin_bit_cast(bf16x8, v);
}
static __device__ __forceinline__ unsigned short bf16u(float f) {
  __hip_bfloat16 h = __float2bfloat16(f);
  return __builtin_bit_cast(unsigned short, h);
}

// ---------------------------------------------------------------------------
// Generic tiled GEMM: out[M,Nc] = A[M,K] @ W[Nc,K]^T (+ bias[Nc])  (fp32)
// ---------------------------------------------------------------------------
__global__ __launch_bounds__(256) void gemm_bt(
    const float* __restrict__ A, const float* __restrict__ W,
    const float* __restrict__ bias, float* __restrict__ out,
    int M, int Nc, int K) {
  __shared__ float As[32][33];
  __shared__ float Bs[32][33];
  const int tx = threadIdx.x & 15;
  const int ty = threadIdx.x >> 4;
  const int row0 = blockIdx.y * 32;
  const int col0 = blockIdx.x * 32;
  float acc00 = 0.f, acc01 = 0.f, acc10 = 0.f, acc11 = 0.f;
  for (int k0 = 0; k0 < K; k0 += 32) {
    const int t = threadIdx.x;
#pragma unroll
    for (int i = 0; i < 4; i++) {
      int idx = t + i * 256;
      int r = idx >> 5, cc = idx & 31;
      As[r][cc] = A[(row0 + r) * K + k0 + cc];
      Bs[r][cc] = W[(col0 + r) * K + k0 + cc];
    }
    __syncthreads();
#pragma unroll
    for (int k = 0; k < 32; k++) {
      float a0 = As[ty * 2][k], a1 = As[ty * 2 + 1][k];
      float b0 = Bs[tx * 2][k], b1 = Bs[tx * 2 + 1][k];
      acc00 += a0 * b0; acc01 += a0 * b1;
      acc10 += a1 * b0; acc11 += a1 * b1;
    }
    __syncthreads();
  }
  int r0 = row0 + ty * 2, c0 = col0 + tx * 2;
  float bb0 = bias ? bias[c0] : 0.f;
  float bb1 = bias ? bias[c0 + 1] : 0.f;
  out[r0 * Nc + c0] = acc00 + bb0;
  out[r0 * Nc + c0 + 1] = acc01 + bb1;
  out[(r0 + 1) * Nc + c0] = acc10 + bb0;
  out[(r0 + 1) * Nc + c0 + 1] = acc11 + bb1;
}

// ---------------------------------------------------------------------------
// Pack q/k: silu+0.5, L2-norm over D=64, bf16, layout [B,H,N,D].
// One wave per (s,b,n,h) row.
// ---------------------------------------------------------------------------
__global__ __launch_bounds__(256) void qk_pack(
    const float* __restrict__ qkv, unsigned short* __restrict__ qp,
    unsigned short* __restrict__ kp) {
  const int wid = (blockIdx.x * 256 + threadIdx.x) >> 6;  // 0..49151
  const int lane = threadIdx.x & 63;
  int s = wid & 1;
  int rest = wid >> 1;
  int h = rest % HH;
  int n = (rest / HH) % NN;
  int b = rest / (HH * NN);
  float z = qkv[(((size_t)(b * NN + n) * 3 + s) * CC) + h * DD + lane];
  float sig = 1.f / (1.f + __expf(-z));
  float r = z * sig + 0.5f;
  float ss = r * r;
#pragma unroll
  for (int off = 32; off >= 1; off >>= 1) ss += __shfl_xor(ss, off, 64);
  r *= rsqrtf(ss);
  unsigned short* dst = s ? kp : qp;
  dst[((size_t)(b * HH + h) * NN + n) * DD + lane] = bf16u(r);
}

// ---------------------------------------------------------------------------
// Pack v transposed: vt[B,H,D,N] bf16, via LDS transpose per 64x64 tile.
// ---------------------------------------------------------------------------
__global__ __launch_bounds__(256) void vt_pack(
    const float* __restrict__ qkv, unsigned short* __restrict__ vt) {
  __shared__ float tile[64][65];
  const int nt = blockIdx.x & 15;
  const int bh = blockIdx.x >> 4;
  const int b = bh / HH, h = bh % HH;
  const int n0 = nt * 64;
  const int t = threadIdx.x;
#pragma unroll
  for (int rep = 0; rep < 16; rep++) {
    int idx = rep * 256 + t;
    int nl = idx >> 6, d = idx & 63;
    tile[d][nl] = qkv[((size_t)(b * NN + n0 + nl) * 3 + 2) * CC + h * DD + d];
  }
  __syncthreads();
#pragma unroll
  for (int rep = 0; rep < 16; rep++) {
    int idx = rep * 256 + t;
    int d = idx >> 6, nl = idx & 63;
    vt[((size_t)bh * DD + d) * NN + n0 + nl] = bf16u(tile[d][nl]);
  }
}

// ---------------------------------------------------------------------------
// Gate: loga[b,h,n] = (n==0) ? 0 : log(1 - sigmoid(x[b,n,:]·Wa[h,:] + ba[h]))
// ---------------------------------------------------------------------------
__global__ __launch_bounds__(256) void gate_kernel(
    const float* __restrict__ x, const float* __restrict__ Wa,
    const float* __restrict__ ba, float* __restrict__ loga) {
  int idx = blockIdx.x * blockDim.x + threadIdx.x;
  if (idx >= BB * NN * HH) return;
  int h = idx % HH;
  int n = (idx / HH) % NN;
  int b = idx / (HH * NN);
  const float* xr = x + (size_t)(b * NN + n) * CC;
  const float* wr = Wa + h * CC;
  float acc = 0.f;
  for (int k = 0; k < CC; k++) acc += xr[k] * wr[k];
  acc += ba[h];
  float a = 1.f - 1.f / (1.f + __expf(-acc));
  float la = (n == 0) ? 0.f : __logf(a);
  loga[(b * HH + h) * NN + n] = la;
}

// ---------------------------------------------------------------------------
// Per-(b,h) inclusive scan of loga -> c[b,h,m], m=0..N (c[0]=0).
// ---------------------------------------------------------------------------
__global__ __launch_bounds__(1024) void scan_kernel(
    const float* __restrict__ loga, float* __restrict__ c) {
  __shared__ float s[NN];
  const int bh = blockIdx.x;
  const int t = threadIdx.x;
  s[t] = loga[bh * NN + t];
  __syncthreads();
#pragma unroll
  for (int off = 1; off < NN; off <<= 1) {
    float prev = (t >= off) ? s[t - off] : 0.f;
    __syncthreads();
    s[t] += prev;
    __syncthreads();
  }
  c[bh * (NN + 1) + t + 1] = s[t];
  if (t == 0) c[bh * (NN + 1)] = 0.f;
}

// ---------------------------------------------------------------------------
// MFMA attention. Block = 256 threads (4 waves), Q-tile 64 rows, KV-tile 64.
// grid = B*H*(N/64) = 384.  Wave w owns q rows w*16..w*16+15 of the tile.
// S = Q·K^T (mfma 16x16x32), mask+scale, A->LDS stripe (bf16), O += A·V.
// Sum-normalization at the end (linear => single streaming pass).
// LDS tiles XOR-swizzled: slot ^= (row&7) at 16B granularity.
// ---------------------------------------------------------------------------
__global__ __launch_bounds__(256) void attn_mfma(
    const unsigned short* __restrict__ qp, const unsigned short* __restrict__ kp,
    const unsigned short* __restrict__ vt, const float* __restrict__ cbuf,
    float* __restrict__ attnout) {
  __shared__ unsigned short Ks[64 * 64];
  __shared__ unsigned short Vs[64 * 64];
  __shared__ unsigned short Aw[4][16 * 64];

  const int qt = blockIdx.x & 15;
  const int bh = blockIdx.x >> 4;
  const int b = bh / HH, h = bh % HH;
  const int qrow0 = qt * 64;
  const int w = threadIdx.x >> 6;
  const int lane = threadIdx.x & 63;
  const int lrow = lane & 15;
  const int lgrp = lane >> 4;

  // Q fragments (A-operand): row = w*16+lrow, k = hk*32 + lgrp*8 + e
  bf16x8 qaf[2];
  {
    const u16x8* qrow_p = (const u16x8*)(qp +
        ((size_t)bh * NN + qrow0 + w * 16 + lrow) * DD);
#pragma unroll
    for (int hk = 0; hk < 2; hk++) qaf[hk] = as_bf16x8(qrow_p[hk * 4 + lgrp]);
  }

  const float* cbh = cbuf + (size_t)bh * (NN + 1);
  float ci[4], ci1[4];
  const int ibase = qrow0 + w * 16 + lgrp * 4;
#pragma unroll
  for (int r = 0; r < 4; r++) {
    ci[r] = cbh[ibase + r];
    ci1[r] = cbh[ibase + r + 1];
  }

  f32x4 oacc[4] = {};
  float rs[4] = {0.f, 0.f, 0.f, 0.f};

  for (int kt = 0; kt < 16; kt++) {
    const int j0 = kt * 64;
    // ---- stage K and Vt tiles (swizzled) ----
#pragma unroll
    for (int rep = 0; rep < 2; rep++) {
      int idx = rep * 256 + threadIdx.x;  // 0..511
      int row = idx >> 3, slot = idx & 7;
      int sw = slot ^ (row & 7);
      *(u16x8*)&Ks[row * 64 + sw * 8] =
          *(const u16x8*)(kp + ((size_t)bh * NN + j0 + row) * DD + slot * 8);
      *(u16x8*)&Vs[row * 64 + sw * 8] =
          *(const u16x8*)(vt + ((size_t)bh * DD + row) * NN + j0 + slot * 8);
    }
    __syncthreads();

    // ---- S = Q·K^T per 16-col tile, mask, stash A (bf16) ----
#pragma unroll
    for (int ct = 0; ct < 4; ct++) {
      const int jl = ct * 16 + lrow;        // local key row
      const int j = j0 + jl;                // global key index
      f32x4 s = {};
      const u16x8* krow_p = (const u16x8*)&Ks[jl * 64];
#pragma unroll
      for (int hk = 0; hk < 2; hk++) {
        bf16x8 kf = as_bf16x8(krow_p[(hk * 4 + lgrp) ^ (jl & 7)]);
        s = __builtin_amdgcn_mfma_f32_16x16x32_bf16(qaf[hk], kf, s, 0, 0, 0);
      }
      const float cj = cbh[j], cj1 = cbh[j + 1];
#pragma unroll
      for (int r = 0; r < 4; r++) {
        const int gi = ibase + r;
        float m = (gi > j) ? __expf(ci[r] - cj)
                 : (gi < j) ? __expf(cj1 - ci1[r]) : 1.0f;
        float av = s[r] * SCALE_F * m;
        rs[r] += av;
        int rowa = lgrp * 4 + r;
        Aw[w][rowa * 64 + (jl ^ ((rowa & 7) << 3))] = bf16u(av);
      }
    }
    // (Aw stripe is wave-private: no barrier needed between write and read)

    // ---- O += A·V ----
#pragma unroll
    for (int jh = 0; jh < 2; jh++) {
      const u16x8* arow_p = (const u16x8*)&Aw[w][lrow * 64];
      bf16x8 af = as_bf16x8(arow_p[(jh * 4 + lgrp) ^ (lrow & 7)]);
#pragma unroll
      for (int dt = 0; dt < 4; dt++) {
        const int dd = dt * 16 + lrow;
        const u16x8* vrow_p = (const u16x8*)&Vs[dd * 64];
        bf16x8 vf = as_bf16x8(vrow_p[(jh * 4 + lgrp) ^ (dd & 7)]);
        oacc[dt] =
            __builtin_amdgcn_mfma_f32_16x16x32_bf16(af, vf, oacc[dt], 0, 0, 0);
      }
    }
    __syncthreads();
  }

  // ---- rowsum reduce across the 16 lanes sharing rows, normalize, store ----
#pragma unroll
  for (int r = 0; r < 4; r++) {
#pragma unroll
    for (int off = 1; off <= 8; off <<= 1) rs[r] += __shfl_xor(rs[r], off, 64);
    rs[r] = 1.f / (rs[r] + 1e-6f);
  }
#pragma unroll
  for (int dt = 0; dt < 4; dt++) {
#pragma unroll
    for (int r = 0; r < 4; r++) {
      const int gi = ibase + r;
      attnout[((size_t)b * NN + gi) * CC + h * DD + dt * 16 + lrow] =
          oacc[dt][r] * rs[r];
    }
  }
}

// ---------------------------------------------------------------------------
extern "C" void kernel_launch(void* const* d_in, const int* in_sizes, int n_in,
                              void* d_out, int out_size, void* d_ws,
                              size_t ws_size, hipStream_t stream) {
  const float* x = (const float*)d_in[0];
  const float* Wqkv = (const float*)d_in[1];
  const float* Wa = (const float*)d_in[2];
  const float* ba = (const float*)d_in[3];
  const float* Wproj = (const float*)d_in[4];
  const float* bproj = (const float*)d_in[5];
  float* out = (float*)d_out;

  float* qkv = (float*)d_ws;                          // B*N*3C fp32
  float* attnout = qkv;                               // alias (qkv dead by then)
  float* loga = qkv + (size_t)BB * NN * 3 * CC;       // B*H*N
  float* cbuf = loga + (size_t)BB * HH * NN;          // B*H*(N+1)
  unsigned short* qp = (unsigned short*)(cbuf + (size_t)BB * HH * (NN + 1));
  unsigned short* kp = qp + (size_t)BB * HH * NN * DD;
  unsigned short* vt = kp + (size_t)BB * HH * NN * DD;

  // 1) qkv = x @ Wqkv^T
  {
    dim3 grid(3 * CC / 32, BB * NN / 32);
    gemm_bt<<<grid, 256, 0, stream>>>(x, Wqkv, nullptr, qkv, BB * NN, 3 * CC, CC);
  }
  // 2) pack q,k (silu-shift-norm, bf16) and v^T (bf16)
  qk_pack<<<12288, 256, 0, stream>>>(qkv, qp, kp);
  vt_pack<<<BB * HH * (NN / 64), 256, 0, stream>>>(qkv, vt);
  // 3) gates
  gate_kernel<<<(BB * NN * HH + 255) / 256, 256, 0, stream>>>(x, Wa, ba, loga);
  // 4) cumsum -> c
  scan_kernel<<<BB * HH, 1024, 0, stream>>>(loga, cbuf);
  // 5) MFMA attention (writes attnout, aliasing qkv region)
  attn_mfma<<<BB * HH * (NN / 64), 256, 0, stream>>>(qp, kp, vt, cbuf, attnout);
  // 6) out = attnout @ Wproj^T + bproj
  {
    dim3 grid(CC / 32, BB * NN / 32);
    gemm_bt<<<grid, 256, 0, stream>>>(attnout, Wproj, bproj, out, BB * NN, CC, CC);
  }
}

// Round 4
// 201.532 us; speedup vs baseline: 7.8146x; 2.2531x over previous
//
#include <hip/hip_runtime.h>
#include <hip/hip_bf16.h>

#define BB 2
#define NN 1024
#define CC 768
#define HH 12
#define DD 64
#define SCALE_F 0.125f

typedef __attribute__((ext_vector_type(8))) __bf16 bf16x8;
typedef __attribute__((ext_vector_type(8))) unsigned short u16x8;
typedef __attribute__((ext_vector_type(4))) unsigned short u16x4;
typedef __attribute__((ext_vector_type(4))) float f32x4;

static __device__ __forceinline__ bf16x8 as_bf16x8(u16x8 v) {
  return __builtin_bit_cast(bf16x8, v);
}
static __device__ __forceinline__ unsigned short bf16u(float f) {
  __hip_bfloat16 h = __float2bfloat16(f);
  return __builtin_bit_cast(unsigned short, h);
}
static __device__ __forceinline__ float bf2f(unsigned short u) {
  unsigned int x = ((unsigned int)u) << 16;
  return __builtin_bit_cast(float, x);
}

// ---------------------------------------------------------------------------
// fp32 -> bf16 pack, float4 -> 4x u16 per thread.
// ---------------------------------------------------------------------------
__global__ __launch_bounds__(256) void pack_bf16(
    const float* __restrict__ in, unsigned short* __restrict__ o, int n4) {
  int i = blockIdx.x * 256 + threadIdx.x;
  if (i >= n4) return;
  float4 v = ((const float4*)in)[i];
  u16x4 u = {bf16u(v.x), bf16u(v.y), bf16u(v.z), bf16u(v.w)};
  *(u16x4*)&o[i * 4] = u;
}

// ---------------------------------------------------------------------------
// MFMA GEMM: out[M,Nc] = A[M,K] @ W[Nc,K]^T (+bias), A/W bf16.
// 128x128 tile, BK=64, 256 threads (4 waves, 2x2 wave grid, 64x64 per wave).
// LDS XOR-swizzled at 16B-slot granularity: slot ^= (row&7).
// ---------------------------------------------------------------------------
template <bool BF16OUT>
__global__ __launch_bounds__(256) void gemm_mfma(
    const unsigned short* __restrict__ A, const unsigned short* __restrict__ W,
    const float* __restrict__ bias, void* __restrict__ outv,
    int M, int Nc, int K) {
  __shared__ unsigned short As[128 * 64];
  __shared__ unsigned short Ws[128 * 64];
  const int row0 = blockIdx.y * 128;
  const int col0 = blockIdx.x * 128;
  const int t = threadIdx.x;
  const int w = t >> 6, lane = t & 63;
  const int lrow = lane & 15, lgrp = lane >> 4;
  const int wr = w >> 1, wc = w & 1;

  f32x4 acc[4][4] = {};

  for (int k0 = 0; k0 < K; k0 += 64) {
#pragma unroll
    for (int i = 0; i < 4; i++) {
      int idx = i * 256 + t;            // 0..1023
      int row = idx >> 3, slot = idx & 7;
      int sw = slot ^ (row & 7);
      *(u16x8*)&As[row * 64 + sw * 8] =
          *(const u16x8*)(A + (size_t)(row0 + row) * K + k0 + slot * 8);
      *(u16x8*)&Ws[row * 64 + sw * 8] =
          *(const u16x8*)(W + (size_t)(col0 + row) * K + k0 + slot * 8);
    }
    __syncthreads();

    bf16x8 af[4][2], bf[4][2];
#pragma unroll
    for (int m = 0; m < 4; m++) {
      int row = wr * 64 + m * 16 + lrow;
      const u16x8* p = (const u16x8*)&As[row * 64];
#pragma unroll
      for (int hk = 0; hk < 2; hk++)
        af[m][hk] = as_bf16x8(p[(hk * 4 + lgrp) ^ (row & 7)]);
    }
#pragma unroll
    for (int n = 0; n < 4; n++) {
      int row = wc * 64 + n * 16 + lrow;
      const u16x8* p = (const u16x8*)&Ws[row * 64];
#pragma unroll
      for (int hk = 0; hk < 2; hk++)
        bf[n][hk] = as_bf16x8(p[(hk * 4 + lgrp) ^ (row & 7)]);
    }
#pragma unroll
    for (int m = 0; m < 4; m++)
#pragma unroll
      for (int n = 0; n < 4; n++) {
        acc[m][n] = __builtin_amdgcn_mfma_f32_16x16x32_bf16(
            af[m][0], bf[n][0], acc[m][n], 0, 0, 0);
        acc[m][n] = __builtin_amdgcn_mfma_f32_16x16x32_bf16(
            af[m][1], bf[n][1], acc[m][n], 0, 0, 0);
      }
    __syncthreads();
  }

#pragma unroll
  for (int n = 0; n < 4; n++) {
    int col = col0 + wc * 64 + n * 16 + lrow;
    float bb = (!BF16OUT && bias) ? bias[col] : 0.f;
#pragma unroll
    for (int m = 0; m < 4; m++) {
      int rbase = row0 + wr * 64 + m * 16 + lgrp * 4;
#pragma unroll
      for (int r = 0; r < 4; r++) {
        float v = acc[m][n][r] + bb;
        if (BF16OUT)
          ((unsigned short*)outv)[(size_t)(rbase + r) * Nc + col] = bf16u(v);
        else
          ((float*)outv)[(size_t)(rbase + r) * Nc + col] = v;
      }
    }
  }
}

// ---------------------------------------------------------------------------
// Pack q/k from bf16 qkv: silu+0.5, L2-norm over D=64, layout [B,H,N,D] bf16.
// One wave per (s,b,n,h) row.
// ---------------------------------------------------------------------------
__global__ __launch_bounds__(256) void qk_pack(
    const unsigned short* __restrict__ qkvb, unsigned short* __restrict__ qp,
    unsigned short* __restrict__ kp) {
  const int wid = (blockIdx.x * 256 + threadIdx.x) >> 6;  // 0..49151
  const int lane = threadIdx.x & 63;
  int s = wid & 1;
  int rest = wid >> 1;
  int h = rest % HH;
  int n = (rest / HH) % NN;
  int b = rest / (HH * NN);
  float z = bf2f(qkvb[(((size_t)(b * NN + n) * 3 + s) * CC) + h * DD + lane]);
  float sig = 1.f / (1.f + __expf(-z));
  float r = z * sig + 0.5f;
  float ss = r * r;
#pragma unroll
  for (int off = 32; off >= 1; off >>= 1) ss += __shfl_xor(ss, off, 64);
  r *= rsqrtf(ss);
  unsigned short* dst = s ? kp : qp;
  dst[((size_t)(b * HH + h) * NN + n) * DD + lane] = bf16u(r);
}

// ---------------------------------------------------------------------------
// Pack v transposed: vt[B,H,D,N] bf16, via LDS transpose per 64x64 tile.
// ---------------------------------------------------------------------------
__global__ __launch_bounds__(256) void vt_pack(
    const unsigned short* __restrict__ qkvb, unsigned short* __restrict__ vt) {
  __shared__ unsigned short tile[64][65];
  const int nt = blockIdx.x & 15;
  const int bh = blockIdx.x >> 4;
  const int b = bh / HH, h = bh % HH;
  const int n0 = nt * 64;
  const int t = threadIdx.x;
#pragma unroll
  for (int rep = 0; rep < 16; rep++) {
    int idx = rep * 256 + t;
    int nl = idx >> 6, d = idx & 63;
    tile[d][nl] = qkvb[((size_t)(b * NN + n0 + nl) * 3 + 2) * CC + h * DD + d];
  }
  __syncthreads();
#pragma unroll
  for (int rep = 0; rep < 16; rep++) {
    int idx = rep * 256 + t;
    int d = idx >> 6, nl = idx & 63;
    vt[((size_t)bh * DD + d) * NN + n0 + nl] = tile[d][nl];
  }
}

// ---------------------------------------------------------------------------
// Gate: loga[b,h,n] = (n==0) ? 0 : log(1 - sigmoid(x[b,n,:]·Wa[h,:] + ba[h]))
// fp32 inputs (gate precision matters: errors accumulate through cumsum).
// ---------------------------------------------------------------------------
__global__ __launch_bounds__(256) void gate_kernel(
    const float* __restrict__ x, const float* __restrict__ Wa,
    const float* __restrict__ ba, float* __restrict__ loga) {
  int idx = blockIdx.x * blockDim.x + threadIdx.x;
  if (idx >= BB * NN * HH) return;
  int h = idx % HH;
  int n = (idx / HH) % NN;
  int b = idx / (HH * NN);
  const float4* xr = (const float4*)(x + (size_t)(b * NN + n) * CC);
  const float4* wr = (const float4*)(Wa + (size_t)h * CC);
  float acc = 0.f;
#pragma unroll 8
  for (int k = 0; k < CC / 4; k++) {
    float4 xv = xr[k], wv = wr[k];
    acc += xv.x * wv.x + xv.y * wv.y + xv.z * wv.z + xv.w * wv.w;
  }
  acc += ba[h];
  float a = 1.f - 1.f / (1.f + __expf(-acc));
  float la = (n == 0) ? 0.f : __logf(a);
  loga[(b * HH + h) * NN + n] = la;
}

// ---------------------------------------------------------------------------
// Per-(b,h) inclusive scan of loga -> c[b,h,m], m=0..N (c[0]=0).
// ---------------------------------------------------------------------------
__global__ __launch_bounds__(1024) void scan_kernel(
    const float* __restrict__ loga, float* __restrict__ c) {
  __shared__ float s[NN];
  const int bh = blockIdx.x;
  const int t = threadIdx.x;
  s[t] = loga[bh * NN + t];
  __syncthreads();
#pragma unroll
  for (int off = 1; off < NN; off <<= 1) {
    float prev = (t >= off) ? s[t - off] : 0.f;
    __syncthreads();
    s[t] += prev;
    __syncthreads();
  }
  c[bh * (NN + 1) + t + 1] = s[t];
  if (t == 0) c[bh * (NN + 1)] = 0.f;
}

// ---------------------------------------------------------------------------
// MFMA attention (see round-1 notes). Writes bf16 attnout [B,N,C].
// ---------------------------------------------------------------------------
__global__ __launch_bounds__(256) void attn_mfma(
    const unsigned short* __restrict__ qp, const unsigned short* __restrict__ kp,
    const unsigned short* __restrict__ vt, const float* __restrict__ cbuf,
    unsigned short* __restrict__ attnout) {
  __shared__ unsigned short Ks[64 * 64];
  __shared__ unsigned short Vs[64 * 64];
  __shared__ unsigned short Aw[4][16 * 64];

  const int qt = blockIdx.x & 15;
  const int bh = blockIdx.x >> 4;
  const int b = bh / HH, h = bh % HH;
  const int qrow0 = qt * 64;
  const int w = threadIdx.x >> 6;
  const int lane = threadIdx.x & 63;
  const int lrow = lane & 15;
  const int lgrp = lane >> 4;

  bf16x8 qaf[2];
  {
    const u16x8* qrow_p = (const u16x8*)(qp +
        ((size_t)bh * NN + qrow0 + w * 16 + lrow) * DD);
#pragma unroll
    for (int hk = 0; hk < 2; hk++) qaf[hk] = as_bf16x8(qrow_p[hk * 4 + lgrp]);
  }

  const float* cbh = cbuf + (size_t)bh * (NN + 1);
  float ci[4], ci1[4];
  const int ibase = qrow0 + w * 16 + lgrp * 4;
#pragma unroll
  for (int r = 0; r < 4; r++) {
    ci[r] = cbh[ibase + r];
    ci1[r] = cbh[ibase + r + 1];
  }

  f32x4 oacc[4] = {};
  float rs[4] = {0.f, 0.f, 0.f, 0.f};

  for (int kt = 0; kt < 16; kt++) {
    const int j0 = kt * 64;
#pragma unroll
    for (int rep = 0; rep < 2; rep++) {
      int idx = rep * 256 + threadIdx.x;
      int row = idx >> 3, slot = idx & 7;
      int sw = slot ^ (row & 7);
      *(u16x8*)&Ks[row * 64 + sw * 8] =
          *(const u16x8*)(kp + ((size_t)bh * NN + j0 + row) * DD + slot * 8);
      *(u16x8*)&Vs[row * 64 + sw * 8] =
          *(const u16x8*)(vt + ((size_t)bh * DD + row) * NN + j0 + slot * 8);
    }
    __syncthreads();

#pragma unroll
    for (int ct = 0; ct < 4; ct++) {
      const int jl = ct * 16 + lrow;
      const int j = j0 + jl;
      f32x4 s = {};
      const u16x8* krow_p = (const u16x8*)&Ks[jl * 64];
#pragma unroll
      for (int hk = 0; hk < 2; hk++) {
        bf16x8 kf = as_bf16x8(krow_p[(hk * 4 + lgrp) ^ (jl & 7)]);
        s = __builtin_amdgcn_mfma_f32_16x16x32_bf16(qaf[hk], kf, s, 0, 0, 0);
      }
      const float cj = cbh[j], cj1 = cbh[j + 1];
#pragma unroll
      for (int r = 0; r < 4; r++) {
        const int gi = ibase + r;
        float m = (gi > j) ? __expf(ci[r] - cj)
                 : (gi < j) ? __expf(cj1 - ci1[r]) : 1.0f;
        float av = s[r] * SCALE_F * m;
        rs[r] += av;
        int rowa = lgrp * 4 + r;
        Aw[w][rowa * 64 + (jl ^ ((rowa & 7) << 3))] = bf16u(av);
      }
    }

#pragma unroll
    for (int jh = 0; jh < 2; jh++) {
      const u16x8* arow_p = (const u16x8*)&Aw[w][lrow * 64];
      bf16x8 af = as_bf16x8(arow_p[(jh * 4 + lgrp) ^ (lrow & 7)]);
#pragma unroll
      for (int dt = 0; dt < 4; dt++) {
        const int dd = dt * 16 + lrow;
        const u16x8* vrow_p = (const u16x8*)&Vs[dd * 64];
        bf16x8 vf = as_bf16x8(vrow_p[(jh * 4 + lgrp) ^ (dd & 7)]);
        oacc[dt] =
            __builtin_amdgcn_mfma_f32_16x16x32_bf16(af, vf, oacc[dt], 0, 0, 0);
      }
    }
    __syncthreads();
  }

#pragma unroll
  for (int r = 0; r < 4; r++) {
#pragma unroll
    for (int off = 1; off <= 8; off <<= 1) rs[r] += __shfl_xor(rs[r], off, 64);
    rs[r] = 1.f / (rs[r] + 1e-6f);
  }
#pragma unroll
  for (int dt = 0; dt < 4; dt++) {
#pragma unroll
    for (int r = 0; r < 4; r++) {
      const int gi = ibase + r;
      attnout[((size_t)b * NN + gi) * CC + h * DD + dt * 16 + lrow] =
          bf16u(oacc[dt][r] * rs[r]);
    }
  }
}

// ---------------------------------------------------------------------------
extern "C" void kernel_launch(void* const* d_in, const int* in_sizes, int n_in,
                              void* d_out, int out_size, void* d_ws,
                              size_t ws_size, hipStream_t stream) {
  const float* x = (const float*)d_in[0];
  const float* Wqkv = (const float*)d_in[1];
  const float* Wa = (const float*)d_in[2];
  const float* ba = (const float*)d_in[3];
  const float* Wproj = (const float*)d_in[4];
  const float* bproj = (const float*)d_in[5];
  float* out = (float*)d_out;

  // workspace layout (~27 MB)
  unsigned short* qkvb = (unsigned short*)d_ws;          // B*N*3C bf16
  float* loga = (float*)(qkvb + (size_t)BB * NN * 3 * CC);
  float* cbuf = loga + (size_t)BB * HH * NN;
  unsigned short* qp = (unsigned short*)(cbuf + (size_t)BB * HH * (NN + 1));
  unsigned short* kp = qp + (size_t)BB * HH * NN * DD;
  unsigned short* vt = kp + (size_t)BB * HH * NN * DD;
  unsigned short* xb = vt + (size_t)BB * HH * NN * DD;
  unsigned short* wqkvb = xb + (size_t)BB * NN * CC;
  unsigned short* wprojb = wqkvb + (size_t)3 * CC * CC;
  unsigned short* attnoutb = qkvb;  // alias: qkvb dead after qk/vt packs

  // 0) bf16 packs of GEMM operands
  pack_bf16<<<(BB * NN * CC / 4 + 255) / 256, 256, 0, stream>>>(
      x, xb, BB * NN * CC / 4);
  pack_bf16<<<(3 * CC * CC / 4 + 255) / 256, 256, 0, stream>>>(
      Wqkv, wqkvb, 3 * CC * CC / 4);
  pack_bf16<<<(CC * CC / 4 + 255) / 256, 256, 0, stream>>>(
      Wproj, wprojb, CC * CC / 4);

  // 1) qkv = x @ Wqkv^T (bf16 MFMA, bf16 out)
  {
    dim3 grid(3 * CC / 128, BB * NN / 128);
    gemm_mfma<true><<<grid, 256, 0, stream>>>(xb, wqkvb, nullptr, qkvb,
                                              BB * NN, 3 * CC, CC);
  }
  // 2) pack q,k (silu-shift-norm) and v^T
  qk_pack<<<12288, 256, 0, stream>>>(qkvb, qp, kp);
  vt_pack<<<BB * HH * (NN / 64), 256, 0, stream>>>(qkvb, vt);
  // 3) gates (fp32)
  gate_kernel<<<(BB * NN * HH + 255) / 256, 256, 0, stream>>>(x, Wa, ba, loga);
  // 4) cumsum -> c
  scan_kernel<<<BB * HH, 1024, 0, stream>>>(loga, cbuf);
  // 5) MFMA attention -> bf16 attnout (aliases qkvb)
  attn_mfma<<<BB * HH * (NN / 64), 256, 0, stream>>>(qp, kp, vt, cbuf, attnoutb);
  // 6) out = attnout @ Wproj^T + bproj (fp32 out)
  {
    dim3 grid(CC / 128, BB * NN / 128);
    gemm_mfma<false><<<grid, 256, 0, stream>>>(attnoutb, wprojb, bproj, out,
                                               BB * NN, CC, CC);
  }
}

// Round 5
// 162.840 us; speedup vs baseline: 9.6714x; 1.2376x over previous
//
#include <hip/hip_runtime.h>
#include <hip/hip_bf16.h>

#define BB 2
#define NN 1024
#define CC 768
#define HH 12
#define DD 64
#define SCALE_F 0.125f

typedef __attribute__((ext_vector_type(8))) __bf16 bf16x8;
typedef __attribute__((ext_vector_type(8))) unsigned short u16x8;
typedef __attribute__((ext_vector_type(4))) unsigned short u16x4;
typedef __attribute__((ext_vector_type(4))) float f32x4;

static __device__ __forceinline__ bf16x8 as_bf16x8(u16x8 v) {
  return __builtin_bit_cast(bf16x8, v);
}
static __device__ __forceinline__ unsigned short bf16u(float f) {
  __hip_bfloat16 h = __float2bfloat16(f);
  return __builtin_bit_cast(unsigned short, h);
}
static __device__ __forceinline__ float bf2f(unsigned short u) {
  unsigned int x = ((unsigned int)u) << 16;
  return __builtin_bit_cast(float, x);
}

// ---------------------------------------------------------------------------
// fp32 -> bf16 pack of three buffers in one launch (x, Wqkv, Wproj).
// Sizes are in float4 units.
// ---------------------------------------------------------------------------
__global__ __launch_bounds__(256) void pack3_bf16(
    const float* __restrict__ s0, unsigned short* __restrict__ d0, int n0,
    const float* __restrict__ s1, unsigned short* __restrict__ d1, int n1,
    const float* __restrict__ s2, unsigned short* __restrict__ d2, int n2) {
  int i = blockIdx.x * 256 + threadIdx.x;
  const float* s;
  unsigned short* d;
  if (i < n0) {
    s = s0; d = d0;
  } else if (i < n0 + n1) {
    i -= n0; s = s1; d = d1;
  } else {
    i -= n0 + n1;
    if (i >= n2) return;
    s = s2; d = d2;
  }
  float4 v = ((const float4*)s)[i];
  u16x4 u = {bf16u(v.x), bf16u(v.y), bf16u(v.z), bf16u(v.w)};
  *(u16x4*)&d[i * 4] = u;
}

// ---------------------------------------------------------------------------
// MFMA GEMM: out[M,Nc] = A[M,K] @ W[Nc,K]^T (+bias), A/W bf16.
// 128x128 tile, BK=64, 256 threads (4 waves, 2x2 wave grid, 64x64 per wave).
// LDS XOR-swizzled at 16B-slot granularity: slot ^= (row&7).
// ---------------------------------------------------------------------------
template <bool BF16OUT>
__global__ __launch_bounds__(256) void gemm_mfma(
    const unsigned short* __restrict__ A, const unsigned short* __restrict__ W,
    const float* __restrict__ bias, void* __restrict__ outv,
    int M, int Nc, int K) {
  __shared__ unsigned short As[128 * 64];
  __shared__ unsigned short Ws[128 * 64];
  const int row0 = blockIdx.y * 128;
  const int col0 = blockIdx.x * 128;
  const int t = threadIdx.x;
  const int w = t >> 6, lane = t & 63;
  const int lrow = lane & 15, lgrp = lane >> 4;
  const int wr = w >> 1, wc = w & 1;

  f32x4 acc[4][4] = {};

  for (int k0 = 0; k0 < K; k0 += 64) {
#pragma unroll
    for (int i = 0; i < 4; i++) {
      int idx = i * 256 + t;            // 0..1023
      int row = idx >> 3, slot = idx & 7;
      int sw = slot ^ (row & 7);
      *(u16x8*)&As[row * 64 + sw * 8] =
          *(const u16x8*)(A + (size_t)(row0 + row) * K + k0 + slot * 8);
      *(u16x8*)&Ws[row * 64 + sw * 8] =
          *(const u16x8*)(W + (size_t)(col0 + row) * K + k0 + slot * 8);
    }
    __syncthreads();

    bf16x8 af[4][2], bf[4][2];
#pragma unroll
    for (int m = 0; m < 4; m++) {
      int row = wr * 64 + m * 16 + lrow;
      const u16x8* p = (const u16x8*)&As[row * 64];
#pragma unroll
      for (int hk = 0; hk < 2; hk++)
        af[m][hk] = as_bf16x8(p[(hk * 4 + lgrp) ^ (row & 7)]);
    }
#pragma unroll
    for (int n = 0; n < 4; n++) {
      int row = wc * 64 + n * 16 + lrow;
      const u16x8* p = (const u16x8*)&Ws[row * 64];
#pragma unroll
      for (int hk = 0; hk < 2; hk++)
        bf[n][hk] = as_bf16x8(p[(hk * 4 + lgrp) ^ (row & 7)]);
    }
#pragma unroll
    for (int m = 0; m < 4; m++)
#pragma unroll
      for (int n = 0; n < 4; n++) {
        acc[m][n] = __builtin_amdgcn_mfma_f32_16x16x32_bf16(
            af[m][0], bf[n][0], acc[m][n], 0, 0, 0);
        acc[m][n] = __builtin_amdgcn_mfma_f32_16x16x32_bf16(
            af[m][1], bf[n][1], acc[m][n], 0, 0, 0);
      }
    __syncthreads();
  }

#pragma unroll
  for (int n = 0; n < 4; n++) {
    int col = col0 + wc * 64 + n * 16 + lrow;
    float bb = (!BF16OUT && bias) ? bias[col] : 0.f;
#pragma unroll
    for (int m = 0; m < 4; m++) {
      int rbase = row0 + wr * 64 + m * 16 + lgrp * 4;
#pragma unroll
      for (int r = 0; r < 4; r++) {
        float v = acc[m][n][r] + bb;
        if (BF16OUT)
          ((unsigned short*)outv)[(size_t)(rbase + r) * Nc + col] = bf16u(v);
        else
          ((float*)outv)[(size_t)(rbase + r) * Nc + col] = v;
      }
    }
  }
}

// ---------------------------------------------------------------------------
// Pack q/k from bf16 qkv: silu+0.5, L2-norm over D=64, layout [B,H,N,D] bf16.
// One wave per (s,b,n,h) row.
// ---------------------------------------------------------------------------
__global__ __launch_bounds__(256) void qk_pack(
    const unsigned short* __restrict__ qkvb, unsigned short* __restrict__ qp,
    unsigned short* __restrict__ kp) {
  const int wid = (blockIdx.x * 256 + threadIdx.x) >> 6;  // 0..49151
  const int lane = threadIdx.x & 63;
  int s = wid & 1;
  int rest = wid >> 1;
  int h = rest % HH;
  int n = (rest / HH) % NN;
  int b = rest / (HH * NN);
  float z = bf2f(qkvb[(((size_t)(b * NN + n) * 3 + s) * CC) + h * DD + lane]);
  float sig = 1.f / (1.f + __expf(-z));
  float r = z * sig + 0.5f;
  float ss = r * r;
#pragma unroll
  for (int off = 32; off >= 1; off >>= 1) ss += __shfl_xor(ss, off, 64);
  r *= rsqrtf(ss);
  unsigned short* dst = s ? kp : qp;
  dst[((size_t)(b * HH + h) * NN + n) * DD + lane] = bf16u(r);
}

// ---------------------------------------------------------------------------
// Pack v transposed: vt[B,H,D,N] bf16, via LDS transpose per 64x64 tile.
// ---------------------------------------------------------------------------
__global__ __launch_bounds__(256) void vt_pack(
    const unsigned short* __restrict__ qkvb, unsigned short* __restrict__ vt) {
  __shared__ unsigned short tile[64][65];
  const int nt = blockIdx.x & 15;
  const int bh = blockIdx.x >> 4;
  const int b = bh / HH, h = bh % HH;
  const int n0 = nt * 64;
  const int t = threadIdx.x;
#pragma unroll
  for (int rep = 0; rep < 16; rep++) {
    int idx = rep * 256 + t;
    int nl = idx >> 6, d = idx & 63;
    tile[d][nl] = qkvb[((size_t)(b * NN + n0 + nl) * 3 + 2) * CC + h * DD + d];
  }
  __syncthreads();
#pragma unroll
  for (int rep = 0; rep < 16; rep++) {
    int idx = rep * 256 + t;
    int d = idx >> 6, nl = idx & 63;
    vt[((size_t)bh * DD + d) * NN + n0 + nl] = tile[d][nl];
  }
}

// ---------------------------------------------------------------------------
// Gate: loga[b,h,n] = (n==0) ? 0 : log(1 - sigmoid(x[b,n,:]·Wa[h,:] + ba[h]))
// Wave per (b,n) row: coalesced x loads, Wa staged in LDS, shuffle reduce.
// ---------------------------------------------------------------------------
__global__ __launch_bounds__(256) void gate_kernel(
    const float* __restrict__ x, const float* __restrict__ Wa,
    const float* __restrict__ ba, float* __restrict__ loga) {
  __shared__ float was[HH][CC];  // 36 KB
  for (int i = threadIdx.x; i < HH * CC; i += 256) was[i / CC][i % CC] = Wa[i];
  __syncthreads();
  const int w = threadIdx.x >> 6, lane = threadIdx.x & 63;
  const int row = blockIdx.x * 4 + w;   // 0..2047
  const int b = row >> 10, n = row & 1023;
  const float* xr = x + (size_t)row * CC;
  float xf[12];
#pragma unroll
  for (int j = 0; j < 12; j++) xf[j] = xr[lane + 64 * j];
  float myacc = 0.f;
#pragma unroll
  for (int h = 0; h < HH; h++) {
    float a = 0.f;
#pragma unroll
    for (int j = 0; j < 12; j++) a += xf[j] * was[h][lane + 64 * j];
#pragma unroll
    for (int off = 32; off >= 1; off >>= 1) a += __shfl_xor(a, off, 64);
    if (lane == h) myacc = a;
  }
  if (lane < HH) {
    float acc = myacc + ba[lane];
    float a = 1.f - 1.f / (1.f + __expf(-acc));
    float la = (n == 0) ? 0.f : __logf(a);
    loga[(b * HH + lane) * NN + n] = la;
  }
}

// ---------------------------------------------------------------------------
// Per-(b,h) inclusive scan of loga -> c[b,h,m], m=0..N (c[0]=0).
// ---------------------------------------------------------------------------
__global__ __launch_bounds__(1024) void scan_kernel(
    const float* __restrict__ loga, float* __restrict__ c) {
  __shared__ float s[NN];
  const int bh = blockIdx.x;
  const int t = threadIdx.x;
  s[t] = loga[bh * NN + t];
  __syncthreads();
#pragma unroll
  for (int off = 1; off < NN; off <<= 1) {
    float prev = (t >= off) ? s[t - off] : 0.f;
    __syncthreads();
    s[t] += prev;
    __syncthreads();
  }
  c[bh * (NN + 1) + t + 1] = s[t];
  if (t == 0) c[bh * (NN + 1)] = 0.f;
}

// ---------------------------------------------------------------------------
// MFMA attention, in-block KV-split for occupancy.
// Block = 256 threads (4 waves), Q-tile 32 rows. Waves {0,2} own rows 0-15,
// {1,3} rows 16-31. Wave-pair js = w>>1 processes KV-half js (8 tiles of 64).
// Partial O and rowsum combined via LDS at the end (sum-norm is linear).
// grid = B*H*(N/32) = 768 blocks = 3 blocks/CU exactly.
// ---------------------------------------------------------------------------
__global__ __launch_bounds__(256) void attn_mfma(
    const unsigned short* __restrict__ qp, const unsigned short* __restrict__ kp,
    const unsigned short* __restrict__ vt, const float* __restrict__ cbuf,
    unsigned short* __restrict__ attnout) {
  __shared__ unsigned short Ks[2][64 * 64];
  __shared__ unsigned short Vs[2][64 * 64];
  __shared__ unsigned short Aw[4][16 * 64];
  __shared__ float Cw[2][64][17];
  __shared__ float Rw[2][64][5];

  const int qt2 = blockIdx.x & 31;
  const int bh = blockIdx.x >> 5;
  const int b = bh / HH, h = bh % HH;
  const int qrow0 = qt2 * 32;
  const int w = threadIdx.x >> 6;
  const int lane = threadIdx.x & 63;
  const int lrow = lane & 15;
  const int lgrp = lane >> 4;
  const int wq = w & 1;    // 16-row half of the Q-tile
  const int js = w >> 1;   // KV half

  bf16x8 qaf[2];
  {
    const u16x8* qrow_p = (const u16x8*)(qp +
        ((size_t)bh * NN + qrow0 + wq * 16 + lrow) * DD);
#pragma unroll
    for (int hk = 0; hk < 2; hk++) qaf[hk] = as_bf16x8(qrow_p[hk * 4 + lgrp]);
  }

  const float* cbh = cbuf + (size_t)bh * (NN + 1);
  float ci[4], ci1[4];
  const int ibase = qrow0 + wq * 16 + lgrp * 4;
#pragma unroll
  for (int r = 0; r < 4; r++) {
    ci[r] = cbh[ibase + r];
    ci1[r] = cbh[ibase + r + 1];
  }

  f32x4 oacc[4] = {};
  float rs[4] = {0.f, 0.f, 0.f, 0.f};

  for (int t = 0; t < 8; t++) {
    // ---- stage tiles t (half 0) and t+8 (half 1): 1024 16B-slots ----
#pragma unroll
    for (int rep = 0; rep < 4; rep++) {
      int idx = rep * 256 + threadIdx.x;
      int buf = idx >> 9, row = (idx >> 3) & 63, slot = idx & 7;
      int sw = slot ^ (row & 7);
      int j0s = (buf * 8 + t) * 64;
      *(u16x8*)&Ks[buf][row * 64 + sw * 8] =
          *(const u16x8*)(kp + ((size_t)bh * NN + j0s + row) * DD + slot * 8);
      *(u16x8*)&Vs[buf][row * 64 + sw * 8] =
          *(const u16x8*)(vt + ((size_t)bh * DD + row) * NN + j0s + slot * 8);
    }
    __syncthreads();

    const int j0 = (js * 8 + t) * 64;

    // ---- S = Q·K^T per 16-col tile, mask, stash A (bf16) ----
#pragma unroll
    for (int ct = 0; ct < 4; ct++) {
      const int jl = ct * 16 + lrow;
      const int j = j0 + jl;
      f32x4 s = {};
      const u16x8* krow_p = (const u16x8*)&Ks[js][jl * 64];
#pragma unroll
      for (int hk = 0; hk < 2; hk++) {
        bf16x8 kf = as_bf16x8(krow_p[(hk * 4 + lgrp) ^ (jl & 7)]);
        s = __builtin_amdgcn_mfma_f32_16x16x32_bf16(qaf[hk], kf, s, 0, 0, 0);
      }
      const float cj = cbh[j], cj1 = cbh[j + 1];
#pragma unroll
      for (int r = 0; r < 4; r++) {
        const int gi = ibase + r;
        float m = (gi > j) ? __expf(ci[r] - cj)
                 : (gi < j) ? __expf(cj1 - ci1[r]) : 1.0f;
        float av = s[r] * SCALE_F * m;
        rs[r] += av;
        int rowa = lgrp * 4 + r;
        Aw[w][rowa * 64 + (jl ^ ((rowa & 7) << 3))] = bf16u(av);
      }
    }

    // ---- O += A·V (Aw stripe is wave-private) ----
#pragma unroll
    for (int jh = 0; jh < 2; jh++) {
      const u16x8* arow_p = (const u16x8*)&Aw[w][lrow * 64];
      bf16x8 af = as_bf16x8(arow_p[(jh * 4 + lgrp) ^ (lrow & 7)]);
#pragma unroll
      for (int dt = 0; dt < 4; dt++) {
        const int dd = dt * 16 + lrow;
        const u16x8* vrow_p = (const u16x8*)&Vs[js][dd * 64];
        bf16x8 vf = as_bf16x8(vrow_p[(jh * 4 + lgrp) ^ (dd & 7)]);
        oacc[dt] =
            __builtin_amdgcn_mfma_f32_16x16x32_bf16(af, vf, oacc[dt], 0, 0, 0);
      }
    }
    __syncthreads();
  }

  // ---- rowsum reduce across the 16 lanes sharing each row ----
#pragma unroll
  for (int r = 0; r < 4; r++) {
#pragma unroll
    for (int off = 1; off <= 8; off <<= 1) rs[r] += __shfl_xor(rs[r], off, 64);
  }

  // ---- combine KV halves: waves 2,3 publish; waves 0,1 finish ----
  if (w >= 2) {
#pragma unroll
    for (int dt = 0; dt < 4; dt++)
#pragma unroll
      for (int r = 0; r < 4; r++) Cw[w - 2][lane][dt * 4 + r] = oacc[dt][r];
#pragma unroll
    for (int r = 0; r < 4; r++) Rw[w - 2][lane][r] = rs[r];
  }
  __syncthreads();
  if (w < 2) {
#pragma unroll
    for (int r = 0; r < 4; r++) {
      rs[r] += Rw[w][lane][r];
      rs[r] = 1.f / (rs[r] + 1e-6f);
    }
#pragma unroll
    for (int dt = 0; dt < 4; dt++) {
#pragma unroll
      for (int r = 0; r < 4; r++) {
        const int gi = ibase + r;
        float val = (oacc[dt][r] + Cw[w][lane][dt * 4 + r]) * rs[r];
        attnout[((size_t)b * NN + gi) * CC + h * DD + dt * 16 + lrow] =
            bf16u(val);
      }
    }
  }
}

// ---------------------------------------------------------------------------
extern "C" void kernel_launch(void* const* d_in, const int* in_sizes, int n_in,
                              void* d_out, int out_size, void* d_ws,
                              size_t ws_size, hipStream_t stream) {
  const float* x = (const float*)d_in[0];
  const float* Wqkv = (const float*)d_in[1];
  const float* Wa = (const float*)d_in[2];
  const float* ba = (const float*)d_in[3];
  const float* Wproj = (const float*)d_in[4];
  const float* bproj = (const float*)d_in[5];
  float* out = (float*)d_out;

  // workspace layout (~27 MB)
  unsigned short* qkvb = (unsigned short*)d_ws;          // B*N*3C bf16
  float* loga = (float*)(qkvb + (size_t)BB * NN * 3 * CC);
  float* cbuf = loga + (size_t)BB * HH * NN;
  unsigned short* qp = (unsigned short*)(cbuf + (size_t)BB * HH * (NN + 1));
  unsigned short* kp = qp + (size_t)BB * HH * NN * DD;
  unsigned short* vt = kp + (size_t)BB * HH * NN * DD;
  unsigned short* xb = vt + (size_t)BB * HH * NN * DD;
  unsigned short* wqkvb = xb + (size_t)BB * NN * CC;
  unsigned short* wprojb = wqkvb + (size_t)3 * CC * CC;
  unsigned short* attnoutb = qkvb;  // alias: qkvb dead after qk/vt packs

  // 0) bf16 packs of x, Wqkv, Wproj (one launch)
  {
    int n0 = BB * NN * CC / 4, n1 = 3 * CC * CC / 4, n2 = CC * CC / 4;
    pack3_bf16<<<(n0 + n1 + n2 + 255) / 256, 256, 0, stream>>>(
        x, xb, n0, Wqkv, wqkvb, n1, Wproj, wprojb, n2);
  }
  // 1) qkv = x @ Wqkv^T (bf16 MFMA, bf16 out)
  {
    dim3 grid(3 * CC / 128, BB * NN / 128);
    gemm_mfma<true><<<grid, 256, 0, stream>>>(xb, wqkvb, nullptr, qkvb,
                                              BB * NN, 3 * CC, CC);
  }
  // 2) pack q,k (silu-shift-norm) and v^T
  qk_pack<<<12288, 256, 0, stream>>>(qkvb, qp, kp);
  vt_pack<<<BB * HH * (NN / 64), 256, 0, stream>>>(qkvb, vt);
  // 3) gates (fp32, wave per row)
  gate_kernel<<<BB * NN / 4, 256, 0, stream>>>(x, Wa, ba, loga);
  // 4) cumsum -> c
  scan_kernel<<<BB * HH, 1024, 0, stream>>>(loga, cbuf);
  // 5) MFMA attention, in-block KV-split -> bf16 attnout (aliases qkvb)
  attn_mfma<<<BB * HH * (NN / 32), 256, 0, stream>>>(qp, kp, vt, cbuf,
                                                     attnoutb);
  // 6) out = attnout @ Wproj^T + bproj (fp32 out)
  {
    dim3 grid(CC / 128, BB * NN / 128);
    gemm_mfma<false><<<grid, 256, 0, stream>>>(attnoutb, wprojb, bproj, out,
                                               BB * NN, CC, CC);
  }
}

// Round 7
// 154.757 us; speedup vs baseline: 10.1765x; 1.0522x over previous
//
#include <hip/hip_runtime.h>
#include <hip/hip_bf16.h>

#define BB 2
#define NN 1024
#define CC 768
#define HH 12
#define DD 64
#define SCALE_F 0.125f

typedef __attribute__((ext_vector_type(8))) __bf16 bf16x8;
typedef __attribute__((ext_vector_type(8))) unsigned short u16x8;
typedef __attribute__((ext_vector_type(4))) unsigned short u16x4;
typedef __attribute__((ext_vector_type(4))) float f32x4;

static __device__ __forceinline__ bf16x8 as_bf16x8(u16x8 v) {
  return __builtin_bit_cast(bf16x8, v);
}
static __device__ __forceinline__ unsigned short bf16u(float f) {
  __hip_bfloat16 h = __float2bfloat16(f);
  return __builtin_bit_cast(unsigned short, h);
}
static __device__ __forceinline__ float bf2f(unsigned short u) {
  unsigned int x = ((unsigned int)u) << 16;
  return __builtin_bit_cast(float, x);
}
// async global->LDS, 16B per lane; LDS dest must be linear in lane order.
static __device__ __forceinline__ void gload16(const void* g, void* l) {
  __builtin_amdgcn_global_load_lds(
      (const __attribute__((address_space(1))) unsigned int*)g,
      (__attribute__((address_space(3))) unsigned int*)l, 16, 0, 0);
}

// ---------------------------------------------------------------------------
// fp32 -> bf16 pack of three buffers in one launch (x, Wqkv, Wproj).
// ---------------------------------------------------------------------------
__global__ __launch_bounds__(256) void pack3_bf16(
    const float* __restrict__ s0, unsigned short* __restrict__ d0, int n0,
    const float* __restrict__ s1, unsigned short* __restrict__ d1, int n1,
    const float* __restrict__ s2, unsigned short* __restrict__ d2, int n2) {
  int i = blockIdx.x * 256 + threadIdx.x;
  const float* s;
  unsigned short* d;
  if (i < n0) {
    s = s0; d = d0;
  } else if (i < n0 + n1) {
    i -= n0; s = s1; d = d1;
  } else {
    i -= n0 + n1;
    if (i >= n2) return;
    s = s2; d = d2;
  }
  float4 v = ((const float4*)s)[i];
  u16x4 u = {bf16u(v.x), bf16u(v.y), bf16u(v.z), bf16u(v.w)};
  *(u16x4*)&d[i * 4] = u;
}

// ---------------------------------------------------------------------------
// MFMA GEMM: out[M,Nc] = A[M,K] @ W[Nc,K]^T (+bias), A/W bf16.
// BMxBN tile, BK=64, 256 threads (4 waves, 2x2, each BM/2 x BN/2).
// Staging via global_load_lds with pre-swizzled SOURCE (LDS dest linear);
// read side XOR slot^(row&7) unchanged (involution).
// ---------------------------------------------------------------------------
template <int BM, int BN, bool BF16OUT>
__global__ __launch_bounds__(256) void gemm_mfma(
    const unsigned short* __restrict__ A, const unsigned short* __restrict__ W,
    const float* __restrict__ bias, void* __restrict__ outv,
    int M, int Nc, int K) {
  __shared__ unsigned short As[BM * 64];
  __shared__ unsigned short Ws[BN * 64];
  constexpr int FM = BM / 32, FN = BN / 32;  // 16x16 frags per wave
  const int row0 = blockIdx.y * BM;
  const int col0 = blockIdx.x * BN;
  const int t = threadIdx.x;
  const int w = t >> 6, lane = t & 63;
  const int lrow = lane & 15, lgrp = lane >> 4;
  const int wr = w >> 1, wc = w & 1;

  f32x4 acc[FM][FN] = {};

  for (int k0 = 0; k0 < K; k0 += 64) {
#pragma unroll
    for (int i = 0; i < BM * 8 / 256; i++) {
      int idx = i * 256 + t;
      int row = idx >> 3, sl = (idx & 7) ^ (row & 7);
      gload16(A + (size_t)(row0 + row) * K + k0 + sl * 8, &As[idx * 8]);
    }
#pragma unroll
    for (int i = 0; i < BN * 8 / 256; i++) {
      int idx = i * 256 + t;
      int row = idx >> 3, sl = (idx & 7) ^ (row & 7);
      gload16(W + (size_t)(col0 + row) * K + k0 + sl * 8, &Ws[idx * 8]);
    }
    __syncthreads();

    bf16x8 af[FM][2], bf[FN][2];
#pragma unroll
    for (int m = 0; m < FM; m++) {
      int row = wr * (BM / 2) + m * 16 + lrow;
      const u16x8* p = (const u16x8*)&As[row * 64];
#pragma unroll
      for (int hk = 0; hk < 2; hk++)
        af[m][hk] = as_bf16x8(p[(hk * 4 + lgrp) ^ (row & 7)]);
    }
#pragma unroll
    for (int n = 0; n < FN; n++) {
      int row = wc * (BN / 2) + n * 16 + lrow;
      const u16x8* p = (const u16x8*)&Ws[row * 64];
#pragma unroll
      for (int hk = 0; hk < 2; hk++)
        bf[n][hk] = as_bf16x8(p[(hk * 4 + lgrp) ^ (row & 7)]);
    }
#pragma unroll
    for (int m = 0; m < FM; m++)
#pragma unroll
      for (int n = 0; n < FN; n++) {
        acc[m][n] = __builtin_amdgcn_mfma_f32_16x16x32_bf16(
            af[m][0], bf[n][0], acc[m][n], 0, 0, 0);
        acc[m][n] = __builtin_amdgcn_mfma_f32_16x16x32_bf16(
            af[m][1], bf[n][1], acc[m][n], 0, 0, 0);
      }
    __syncthreads();
  }

#pragma unroll
  for (int n = 0; n < FN; n++) {
    int col = col0 + wc * (BN / 2) + n * 16 + lrow;
    float bb = (!BF16OUT && bias) ? bias[col] : 0.f;
#pragma unroll
    for (int m = 0; m < FM; m++) {
      int rbase = row0 + wr * (BM / 2) + m * 16 + lgrp * 4;
#pragma unroll
      for (int r = 0; r < 4; r++) {
        float v = acc[m][n][r] + bb;
        if (BF16OUT)
          ((unsigned short*)outv)[(size_t)(rbase + r) * Nc + col] = bf16u(v);
        else
          ((float*)outv)[(size_t)(rbase + r) * Nc + col] = v;
      }
    }
  }
}

// ---------------------------------------------------------------------------
// Fused q/k silu-norm pack + v^T pack (one launch).
// Blocks [0,12288): qk (wave per (s,b,n,h) row).
// Blocks [12288,12672): v^T via LDS transpose per 64x64 tile.
// ---------------------------------------------------------------------------
__global__ __launch_bounds__(256) void qkv_pack(
    const unsigned short* __restrict__ qkvb, unsigned short* __restrict__ qp,
    unsigned short* __restrict__ kp, unsigned short* __restrict__ vt) {
  __shared__ unsigned short tile[64][65];
  if (blockIdx.x < 12288) {
    const int wid = (blockIdx.x * 256 + threadIdx.x) >> 6;  // 0..49151
    const int lane = threadIdx.x & 63;
    int s = wid & 1;
    int rest = wid >> 1;
    int h = rest % HH;
    int n = (rest / HH) % NN;
    int b = rest / (HH * NN);
    float z = bf2f(qkvb[(((size_t)(b * NN + n) * 3 + s) * CC) + h * DD + lane]);
    float sig = 1.f / (1.f + __expf(-z));
    float r = z * sig + 0.5f;
    float ss = r * r;
#pragma unroll
    for (int off = 32; off >= 1; off >>= 1) ss += __shfl_xor(ss, off, 64);
    r *= rsqrtf(ss);
    unsigned short* dst = s ? kp : qp;
    dst[((size_t)(b * HH + h) * NN + n) * DD + lane] = bf16u(r);
  } else {
    const int blk = blockIdx.x - 12288;       // 0..383
    const int nt = blk & 15;
    const int bh = blk >> 4;
    const int b = bh / HH, h = bh % HH;
    const int n0 = nt * 64;
    const int t = threadIdx.x;
#pragma unroll
    for (int rep = 0; rep < 16; rep++) {
      int idx = rep * 256 + t;
      int nl = idx >> 6, d = idx & 63;
      tile[d][nl] =
          qkvb[((size_t)(b * NN + n0 + nl) * 3 + 2) * CC + h * DD + d];
    }
    __syncthreads();
#pragma unroll
    for (int rep = 0; rep < 16; rep++) {
      int idx = rep * 256 + t;
      int d = idx >> 6, nl = idx & 63;
      vt[((size_t)bh * DD + d) * NN + n0 + nl] = tile[d][nl];
    }
  }
}

// ---------------------------------------------------------------------------
// Gate: loga[b,h,n] = (n==0) ? 0 : log2(1 - sigmoid(x[b,n,:]·Wa[h,:] + ba[h]))
// (log2 basis; mask later uses exp2 — identical product, cheaper exp.)
// ---------------------------------------------------------------------------
__global__ __launch_bounds__(256) void gate_kernel(
    const float* __restrict__ x, const float* __restrict__ Wa,
    const float* __restrict__ ba, float* __restrict__ loga) {
  __shared__ float was[HH][CC];  // 36 KB
  for (int i = threadIdx.x; i < HH * CC; i += 256) was[i / CC][i % CC] = Wa[i];
  __syncthreads();
  const int w = threadIdx.x >> 6, lane = threadIdx.x & 63;
  const int row = blockIdx.x * 4 + w;   // 0..2047
  const int b = row >> 10, n = row & 1023;
  const float* xr = x + (size_t)row * CC;
  float xf[12];
#pragma unroll
  for (int j = 0; j < 12; j++) xf[j] = xr[lane + 64 * j];
  float myacc = 0.f;
#pragma unroll
  for (int h = 0; h < HH; h++) {
    float a = 0.f;
#pragma unroll
    for (int j = 0; j < 12; j++) a += xf[j] * was[h][lane + 64 * j];
#pragma unroll
    for (int off = 32; off >= 1; off >>= 1) a += __shfl_xor(a, off, 64);
    if (lane == h) myacc = a;
  }
  if (lane < HH) {
    float acc = myacc + ba[lane];
    float a = 1.f - 1.f / (1.f + __expf(-acc));
    float la = (n == 0) ? 0.f : log2f(a);
    loga[(b * HH + lane) * NN + n] = la;
  }
}

// ---------------------------------------------------------------------------
// Wave-per-(b,h) inclusive scan of loga -> c[b,h,m], m=0..N (c[0]=0).
// 16 elems/lane serial + shfl_up prefix of lane totals. No barriers.
// ---------------------------------------------------------------------------
__global__ __launch_bounds__(64) void scan_kernel(
    const float* __restrict__ loga, float* __restrict__ c) {
  const int bh = blockIdx.x;
  const int lane = threadIdx.x;
  const float4* s4 = (const float4*)(loga + (size_t)bh * NN + lane * 16);
  float v[16];
#pragma unroll
  for (int q = 0; q < 4; q++) {
    float4 t = s4[q];
    v[q * 4 + 0] = t.x; v[q * 4 + 1] = t.y;
    v[q * 4 + 2] = t.z; v[q * 4 + 3] = t.w;
  }
  float run = 0.f;
#pragma unroll
  for (int e = 0; e < 16; e++) { run += v[e]; v[e] = run; }
  float tot = run;
#pragma unroll
  for (int off = 1; off < 64; off <<= 1) {
    float nb = __shfl_up(tot, off, 64);
    if (lane >= off) tot += nb;
  }
  float excl = tot - run;
  float* dst = c + (size_t)bh * (NN + 1);
  if (lane == 0) dst[0] = 0.f;
#pragma unroll
  for (int e = 0; e < 16; e++) dst[1 + lane * 16 + e] = v[e] + excl;
}

// ---------------------------------------------------------------------------
// MFMA attention, in-block KV-split (4 waves: wq = w&1 Q-half, js = w>>1 KV
// half). Staging via global_load_lds, source pre-swizzled. Partial O/rowsum
// combined via LDS (sum-norm is linear). grid = B*H*(N/32) = 768 blocks.
// ---------------------------------------------------------------------------
__global__ __launch_bounds__(256) void attn_mfma(
    const unsigned short* __restrict__ qp, const unsigned short* __restrict__ kp,
    const unsigned short* __restrict__ vt, const float* __restrict__ cbuf,
    unsigned short* __restrict__ attnout) {
  __shared__ unsigned short Ks[2][64 * 64];
  __shared__ unsigned short Vs[2][64 * 64];
  __shared__ unsigned short Aw[4][16 * 64];
  __shared__ float Cw[2][64][17];
  __shared__ float Rw[2][64][5];

  const int qt2 = blockIdx.x & 31;
  const int bh = blockIdx.x >> 5;
  const int b = bh / HH, h = bh % HH;
  const int qrow0 = qt2 * 32;
  const int w = threadIdx.x >> 6;
  const int lane = threadIdx.x & 63;
  const int lrow = lane & 15;
  const int lgrp = lane >> 4;
  const int wq = w & 1;    // 16-row half of the Q-tile
  const int js = w >> 1;   // KV half

  bf16x8 qaf[2];
  {
    const u16x8* qrow_p = (const u16x8*)(qp +
        ((size_t)bh * NN + qrow0 + wq * 16 + lrow) * DD);
#pragma unroll
    for (int hk = 0; hk < 2; hk++) qaf[hk] = as_bf16x8(qrow_p[hk * 4 + lgrp]);
  }

  const float* cbh = cbuf + (size_t)bh * (NN + 1);
  float ci[4], ci1[4];
  const int ibase = qrow0 + wq * 16 + lgrp * 4;
#pragma unroll
  for (int r = 0; r < 4; r++) {
    ci[r] = cbh[ibase + r];
    ci1[r] = cbh[ibase + r + 1];
  }

  f32x4 oacc[4] = {};
  float rs[4] = {0.f, 0.f, 0.f, 0.f};

  unsigned short* ksf = &Ks[0][0];
  unsigned short* vsf = &Vs[0][0];

  for (int t = 0; t < 8; t++) {
    // ---- stage tiles t (half 0) and t+8 (half 1) via global_load_lds ----
#pragma unroll
    for (int rep = 0; rep < 4; rep++) {
      int idx = rep * 256 + threadIdx.x;          // 0..1023
      int buf = idx >> 9, row = (idx >> 3) & 63;
      int sl = (idx & 7) ^ (row & 7);             // pre-swizzled source slot
      int j0s = (buf * 8 + t) * 64;
      gload16(kp + ((size_t)bh * NN + j0s + row) * DD + sl * 8, ksf + idx * 8);
      gload16(vt + ((size_t)bh * DD + row) * NN + j0s + sl * 8, vsf + idx * 8);
    }
    __syncthreads();

    const int j0 = (js * 8 + t) * 64;

    // ---- S = Q·K^T per 16-col tile, mask (exp2 of cumsum diff), stash A ----
#pragma unroll
    for (int ct = 0; ct < 4; ct++) {
      const int jl = ct * 16 + lrow;
      const int j = j0 + jl;
      f32x4 s = {};
      const u16x8* krow_p = (const u16x8*)&Ks[js][jl * 64];
#pragma unroll
      for (int hk = 0; hk < 2; hk++) {
        bf16x8 kf = as_bf16x8(krow_p[(hk * 4 + lgrp) ^ (jl & 7)]);
        s = __builtin_amdgcn_mfma_f32_16x16x32_bf16(qaf[hk], kf, s, 0, 0, 0);
      }
      const float cj = cbh[j], cj1 = cbh[j + 1];
#pragma unroll
      for (int r = 0; r < 4; r++) {
        const int gi = ibase + r;
        float m = (gi > j) ? exp2f(ci[r] - cj)
                 : (gi < j) ? exp2f(cj1 - ci1[r]) : 1.0f;
        float av = s[r] * SCALE_F * m;
        rs[r] += av;
        int rowa = lgrp * 4 + r;
        Aw[w][rowa * 64 + (jl ^ ((rowa & 7) << 3))] = bf16u(av);
      }
    }

    // ---- O += A·V (Aw stripe is wave-private) ----
#pragma unroll
    for (int jh = 0; jh < 2; jh++) {
      const u16x8* arow_p = (const u16x8*)&Aw[w][lrow * 64];
      bf16x8 af = as_bf16x8(arow_p[(jh * 4 + lgrp) ^ (lrow & 7)]);
#pragma unroll
      for (int dt = 0; dt < 4; dt++) {
        const int dd = dt * 16 + lrow;
        const u16x8* vrow_p = (const u16x8*)&Vs[js][dd * 64];
        bf16x8 vf = as_bf16x8(vrow_p[(jh * 4 + lgrp) ^ (dd & 7)]);
        oacc[dt] =
            __builtin_amdgcn_mfma_f32_16x16x32_bf16(af, vf, oacc[dt], 0, 0, 0);
      }
    }
    __syncthreads();
  }

  // ---- rowsum reduce across the 16 lanes sharing each row ----
#pragma unroll
  for (int r = 0; r < 4; r++) {
#pragma unroll
    for (int off = 1; off <= 8; off <<= 1) rs[r] += __shfl_xor(rs[r], off, 64);
  }

  // ---- combine KV halves: waves 2,3 publish; waves 0,1 finish ----
  if (w >= 2) {
#pragma unroll
    for (int dt = 0; dt < 4; dt++)
#pragma unroll
      for (int r = 0; r < 4; r++) Cw[w - 2][lane][dt * 4 + r] = oacc[dt][r];
#pragma unroll
    for (int r = 0; r < 4; r++) Rw[w - 2][lane][r] = rs[r];
  }
  __syncthreads();
  if (w < 2) {
#pragma unroll
    for (int r = 0; r < 4; r++) {
      rs[r] += Rw[w][lane][r];
      rs[r] = 1.f / (rs[r] + 1e-6f);
    }
#pragma unroll
    for (int dt = 0; dt < 4; dt++) {
#pragma unroll
      for (int r = 0; r < 4; r++) {
        const int gi = ibase + r;
        float val = (oacc[dt][r] + Cw[w][lane][dt * 4 + r]) * rs[r];
        attnout[((size_t)b * NN + gi) * CC + h * DD + dt * 16 + lrow] =
            bf16u(val);
      }
    }
  }
}

// ---------------------------------------------------------------------------
extern "C" void kernel_launch(void* const* d_in, const int* in_sizes, int n_in,
                              void* d_out, int out_size, void* d_ws,
                              size_t ws_size, hipStream_t stream) {
  const float* x = (const float*)d_in[0];
  const float* Wqkv = (const float*)d_in[1];
  const float* Wa = (const float*)d_in[2];
  const float* ba = (const float*)d_in[3];
  const float* Wproj = (const float*)d_in[4];
  const float* bproj = (const float*)d_in[5];
  float* out = (float*)d_out;

  // workspace layout (~27 MB)
  unsigned short* qkvb = (unsigned short*)d_ws;          // B*N*3C bf16
  float* loga = (float*)(qkvb + (size_t)BB * NN * 3 * CC);
  float* cbuf = loga + (size_t)BB * HH * NN;
  unsigned short* qp = (unsigned short*)(cbuf + (size_t)BB * HH * (NN + 1));
  unsigned short* kp = qp + (size_t)BB * HH * NN * DD;
  unsigned short* vt = kp + (size_t)BB * HH * NN * DD;
  unsigned short* xb = vt + (size_t)BB * HH * NN * DD;
  unsigned short* wqkvb = xb + (size_t)BB * NN * CC;
  unsigned short* wprojb = wqkvb + (size_t)3 * CC * CC;
  unsigned short* attnoutb = qkvb;  // alias: qkvb dead after qkv_pack

  // 0) bf16 packs of x, Wqkv, Wproj (one launch)
  {
    int n0 = BB * NN * CC / 4, n1 = 3 * CC * CC / 4, n2 = CC * CC / 4;
    pack3_bf16<<<(n0 + n1 + n2 + 255) / 256, 256, 0, stream>>>(
        x, xb, n0, Wqkv, wqkvb, n1, Wproj, wprojb, n2);
  }
  // 1) qkv = x @ Wqkv^T (bf16 MFMA, bf16 out)
  {
    dim3 grid(3 * CC / 128, BB * NN / 128);
    gemm_mfma<128, 128, true><<<grid, 256, 0, stream>>>(
        xb, wqkvb, nullptr, qkvb, BB * NN, 3 * CC, CC);
  }
  // 2) fused q/k silu-norm pack + v^T pack
  qkv_pack<<<12672, 256, 0, stream>>>(qkvb, qp, kp, vt);
  // 3) gates (fp32, wave per row; log2 basis)
  gate_kernel<<<BB * NN / 4, 256, 0, stream>>>(x, Wa, ba, loga);
  // 4) cumsum -> c (wave per (b,h))
  scan_kernel<<<BB * HH, 64, 0, stream>>>(loga, cbuf);
  // 5) MFMA attention, in-block KV-split -> bf16 attnout (aliases qkvb)
  attn_mfma<<<BB * HH * (NN / 32), 256, 0, stream>>>(qp, kp, vt, cbuf,
                                                     attnoutb);
  // 6) out = attnout @ Wproj^T + bproj (fp32 out, 64x64 tiles for occupancy)
  {
    dim3 grid(CC / 64, BB * NN / 64);
    gemm_mfma<64, 64, false><<<grid, 256, 0, stream>>>(
        attnoutb, wprojb, bproj, out, BB * NN, CC, CC);
  }
}